// Round 12
// baseline (8100.591 us; speedup 1.0000x reference)
//
#include <hip/hip_runtime.h>

typedef unsigned short u16;
typedef float f32x4 __attribute__((ext_vector_type(4)));
typedef __bf16 bf16x8 __attribute__((ext_vector_type(8)));

#define NN   4096
#define NLVL 6
#define LDK  72   // padded LDS k-stride for generic gemm only

static __device__ __forceinline__ u16 f2bf(float f) {
    unsigned int u = __float_as_uint(f);
    u += 0x7fffu + ((u >> 16) & 1u);
    return (u16)(u >> 16);
}
static __device__ __forceinline__ float bf2f(u16 v) {
    return __uint_as_float(((unsigned int)v) << 16);
}
static __device__ __forceinline__ float sigm(float x) { return 1.0f / (1.0f + __expf(-x)); }
static __device__ __forceinline__ float tanh_(float x) { return 2.0f / (1.0f + __expf(-2.0f * x)) - 1.0f; }

// ---------------- weight packing (once per launch) ----------------
// Block-major (HW-verified): W2[chain][block][512], block = ct*16 + ks.
// Block holds a 16x32 tile row-major [lro][kk]; lane (lro,q4) reads its A-fragment
// at element offset lro*32 + q4*8. C = 4*j + ig gate-interleaved.
__global__ void pack_wcomb(const float* __restrict__ kf, const float* __restrict__ rf,
                           const float* __restrict__ kb, const float* __restrict__ rb,
                           const float* __restrict__ bfw, const float* __restrict__ bbw,
                           u16* __restrict__ W2, float* __restrict__ biasP) {
    int C = blockIdx.x, chain = blockIdx.y;
    int g = chain >> 1, dir = chain & 1;
    int ig = C & 3, j = C >> 2;
    int oc = ig * 256 + j;
    int ct = C >> 4, lro = C & 15;
    const float* Ks = (dir ? kb : kf) + g * (256 * 1024);
    const float* Rs = (dir ? rb : rf) + g * (256 * 1024);
    u16* base = W2 + (size_t)chain * (1024 * 512);
    for (int it = 0; it < 2; ++it) {
        int k = it * 256 + threadIdx.x;
        float v = (k < 256) ? Ks[k * 1024 + oc] : Rs[(k - 256) * 1024 + oc];
        int ks = k >> 5, kk = k & 31;
        base[(size_t)(ct * 16 + ks) * 512 + lro * 32 + kk] = f2bf(v);
    }
    if (threadIdx.x == 0) biasP[chain * 1024 + C] = (dir ? bbw : bfw)[g * 1024 + oc];
}

// fcT[g][n][k] = fc[g][k][n]
__global__ void pack_fcT(const float* __restrict__ fck, u16* __restrict__ fcT) {
    int n = blockIdx.x, g = blockIdx.y;
    u16* dst = fcT + (g * 256 + n) * 512;
    for (int it = 0; it < 2; ++it) {
        int k = it * 256 + threadIdx.x;
        dst[k] = f2bf(fck[(g * 512 + k) * 256 + n]);
    }
}

// WkT[C][k] = W_kernel[k][C]
__global__ void pack_wkT(const float* __restrict__ Wk, u16* __restrict__ WkT) {
    int C = blockIdx.x;
    int k = threadIdx.x;
    WkT[C * 256 + k] = f2bf(Wk[k * 1024 + C]);
}

// h0c[chain][256] bf16, c0c[chain][256] f32 broadcast-init vectors
__global__ void pack_init(const float* __restrict__ ihf, const float* __restrict__ icf,
                          const float* __restrict__ ihb, const float* __restrict__ icb,
                          u16* __restrict__ h0c, float* __restrict__ c0c) {
    int chain = blockIdx.x, j = threadIdx.x;
    int g = chain >> 1, dir = chain & 1;
    h0c[chain * 256 + j] = f2bf((dir ? ihb : ihf)[g * 256 + j]);
    c0c[chain * 256 + j] = (dir ? icb : icf)[g * 256 + j];
}

// ---------------- length histogram + counting sort (once) ----------------
__global__ void compute_len(const int* __restrict__ indices, int* __restrict__ len_all,
                            int* __restrict__ hist) {
    int lvl = blockIdx.y;
    int b = blockIdx.x * 128 + threadIdx.x;
    const int* ind = indices + ((size_t)lvl * NN + b) * 8;
    int len = 0;
#pragma unroll
    for (int k = 0; k < 8; ++k) len += (ind[k] != -1) ? 1 : 0;
    len_all[lvl * NN + b] = len;
    atomicAdd(&hist[lvl * 8 + (len - 1)], 1);
}

// descending-length counting sort: perm[i] = original node, len_p sorted
__global__ void build_perm(const int* __restrict__ len_all, const int* __restrict__ hist,
                           int* __restrict__ perm, int* __restrict__ len_p) {
    int lvl = blockIdx.x;
    __shared__ int off[9];
    __shared__ int cur[9];
    if (threadIdx.x == 0) {
        int s = 0;
        for (int L = 8; L >= 1; --L) { off[L] = s; cur[L] = 0; s += hist[lvl * 8 + L - 1]; }
    }
    __syncthreads();
    for (int b = threadIdx.x; b < NN; b += blockDim.x) {
        int len = len_all[lvl * NN + b];
        int pos = off[len] + atomicAdd(&cur[len], 1);
        perm[lvl * NN + pos] = b;
        len_p[lvl * NN + pos] = len;
    }
}

// ---------------- per-level prep (all in permuted row space) ----------------
__global__ void convert_x(const float* __restrict__ x, const int* __restrict__ perm,
                          u16* __restrict__ xb) {
    int i = blockIdx.x;
    int orig = perm[i];
    xb[i * 256 + threadIdx.x] = f2bf(x[orig * 256 + threadIdx.x]);
}

__global__ void gather_children(const int* __restrict__ ind, const int* __restrict__ perm,
                                const u16* __restrict__ h_prev, u16* __restrict__ Hc) {
    int i = blockIdx.x;
    int orig = perm[i];
    int k = threadIdx.x >> 5;
    int c0 = (threadIdx.x & 31) * 8;
    int iv = ind[orig * 8 + k];
    uint4 v = make_uint4(0u, 0u, 0u, 0u);
    if (iv >= 1) v = *(const uint4*)(h_prev + (iv - 1) * 256 + c0);
    *(uint4*)(Hc + (i * 8 + k) * 256 + c0) = v;
}

// ---------------- persistent fused BiLSTM v7 (register-lean, spill-free target) ----------------
// 512 blocks x 512 threads; chain = bid&7 (XCD-pinned), 64-row batch tile, 1 block/CU.
// Wave owns ONE ct-row (16 C) x 64 batch per ch-iteration (8 iters -> all 1024 C).
// Per-thread regs: c_reg 32 + acc 16 + av pf 12 + bv 16 transient + addr ~25 < 128 cap.
// A: block-major W2 streamed L2 -> VGPR, depth-3 rotating prefetch. NO weight LDS.
// B: double-buffered LDS, rotation slot=(chunk+row)&31, conflict-free b128 R/W.
// ONE barrier per time step.
__global__ __launch_bounds__(512, 2)
void lstm_persist(const u16* __restrict__ Hc,
                  const u16* __restrict__ W2, const float* __restrict__ biasP,
                  const u16* __restrict__ h0c, const float* __restrict__ c0c,
                  const int* __restrict__ len_p,
                  u16* __restrict__ Y0, u16* __restrict__ ylast) {
    __shared__ __align__(16) u16 xS[2][64 * 256];   // 2 x 32 KB
    __shared__ __align__(16) u16 hS[2][64 * 256];   // 2 x 32 KB
    const int bid = blockIdx.x;
    const int chain = bid & 7;
    const int bi0 = (bid >> 3) * 64;
    const int dir = chain & 1;
    const int tid = threadIdx.x;
    const int l = tid & 63;
    const int wave = tid >> 6;
    const int lro = l & 15;
    const int q4 = l >> 4;

    const int maxlen = len_p[bi0];       // sorted descending
    const int srow = tid >> 3;           // staging/emit: row 0..63
    const int sseg = tid & 7;            // 4 chunks of 16B each
    const int slen = len_p[bi0 + srow];

    const u16* Wf = W2 + (size_t)chain * (1024 * 512);
    const int lq = lro * 32 + q4 * 8;    // A-fragment offset within a 512-elem block

    // prologue: hS[0] = rotated h0 broadcast; xS[0] = rotated x(t=0)
    {
        const u16* h0 = h0c + chain * 256;
#pragma unroll
        for (int i = 0; i < 4; ++i) {
            int c = sseg * 4 + i;
            int slot = (c + srow) & 31;
            *(uint4*)((char*)hS[0] + srow * 512 + slot * 16) = *(const uint4*)(h0 + c * 8);
        }
        int ts0 = dir ? (slen - 1) : 0;
        ts0 = ts0 < 0 ? 0 : ts0;
        const u16* src = Hc + ((size_t)(bi0 + srow) * 8 + ts0) * 256;
#pragma unroll
        for (int i = 0; i < 4; ++i) {
            int c = sseg * 4 + i;
            int slot = (c + srow) & 31;
            *(uint4*)((char*)xS[0] + srow * 512 + slot * 16) = *(const uint4*)(src + c * 8);
        }
    }
    // c state in regs: c_reg[ch][n], channel jj = (ch*8+wave)*4 + q4 ; cols n*16+lro
    float c_reg[8][4];
#pragma unroll
    for (int ch = 0; ch < 8; ++ch) {
        float cv = c0c[chain * 256 + (ch * 8 + wave) * 4 + q4];
#pragma unroll
        for (int n = 0; n < 4; ++n) c_reg[ch][n] = cv;
    }
    const f32x4 zz = {0.f, 0.f, 0.f, 0.f};
    __syncthreads();

    for (int t = 0; t < maxlen; ++t) {
        const int rb = t & 1;
        const char* xB = (const char*)xS[rb];
        const char* hB = (const char*)hS[rb];
        char* hN = (char*)hS[rb ^ 1];

#pragma unroll
        for (int ch = 0; ch < 8; ++ch) {
            const int ct = ch * 8 + wave;
            const u16* wb = Wf + (size_t)(ct * 16) * 512 + lq;   // block base (ks=0)

            f32x4 acc[4];
#pragma unroll
            for (int n = 0; n < 4; ++n) acc[n] = zz;

            // depth-3 rotating av prefetch (2 loads in flight)
            bf16x8 pf[3];
            pf[0] = *(const bf16x8*)(wb);
            pf[1] = *(const bf16x8*)(wb + 512);
#pragma unroll
            for (int ks = 0; ks < 16; ++ks) {
                if (ks + 2 < 16)
                    pf[(ks + 2) % 3] = *(const bf16x8*)(wb + (size_t)(ks + 2) * 512);
                bf16x8 avc = pf[ks % 3];
                const char* bB = (ks < 8) ? xB : hB;
                const int cb = (ks & 7) * 4 + q4;   // 16B chunk index
                bf16x8 bv[4];
#pragma unroll
                for (int n = 0; n < 4; ++n) {
                    int row = n * 16 + lro;
                    int slot = (cb + row) & 31;
                    bv[n] = *(const bf16x8*)(bB + row * 512 + slot * 16);
                }
#pragma unroll
                for (int n = 0; n < 4; ++n)
                    acc[n] = __builtin_amdgcn_mfma_f32_16x16x32_bf16(avc, bv[n], acc[n], 0, 0, 0);
            }
            // fused cell epilogue + rotated scatter into hS[rb^1]
            {
                int Crow = ct * 16 + q4 * 4;
                float4 bias = *(const float4*)(biasP + chain * 1024 + Crow);
                int jj = ct * 4 + q4;
                int chunk = jj >> 3;
                int jb = (jj & 7) * 2;               // byte offset within 16B chunk
#pragma unroll
                for (int n = 0; n < 4; ++n) {
                    float zi = acc[n][0] + bias.x;
                    float zf = acc[n][1] + bias.y;
                    float zg = acc[n][2] + bias.z;
                    float zo = acc[n][3] + bias.w;
                    float cn = sigm(zf) * c_reg[ch][n] + sigm(zi) * tanh_(zg);
                    float hn = sigm(zo) * tanh_(cn);
                    c_reg[ch][n] = cn;
                    unsigned int hb = (unsigned int)f2bf(hn);
                    unsigned int other = (unsigned int)__shfl_xor((int)hb, 16);
                    if ((q4 & 1) == 0) {             // even q4 -> even jj -> 4B-aligned
                        int bl = n * 16 + lro;
                        int slot = (chunk + bl) & 31;
                        *(unsigned int*)(hN + bl * 512 + slot * 16 + jb) = hb | (other << 16);
                    }
                }
            }
        }
        // stage x for t+1 into xS[rb^1]
        if (t + 1 < maxlen) {
            int ts = dir ? (slen - 2 - t) : (t + 1);
            ts = ts < 0 ? 0 : (ts > 7 ? 7 : ts);
            const u16* src = Hc + ((size_t)(bi0 + srow) * 8 + ts) * 256;
            char* xN = (char*)xS[rb ^ 1];
#pragma unroll
            for (int i = 0; i < 4; ++i) {
                int c = sseg * 4 + i;
                int slot = (c + srow) & 31;
                *(uint4*)(xN + srow * 512 + slot * 16) = *(const uint4*)(src + c * 8);
            }
        }
        __syncthreads();                 // h_t complete + x_{t+1} staged

        // emit coalesced outputs from hS[rb^1] (holds h of step t)
        const char* hE = (const char*)hS[rb ^ 1];
        if (chain < 2) {
            u16* dst = Y0 + ((size_t)(bi0 + srow) * 8 + t) * 512 + dir * 256 + sseg * 32;
#pragma unroll
            for (int i = 0; i < 4; ++i) {
                int c = sseg * 4 + i;
                int slot = (c + srow) & 31;
                *(uint4*)(dst + i * 8) = *(const uint4*)(hE + srow * 512 + slot * 16);
            }
        } else if (t == slen - 1) {
            u16* dst = ylast + (size_t)((chain >> 1) - 1) * (NN * 512)
                     + (size_t)(bi0 + srow) * 512 + dir * 256 + sseg * 32;
#pragma unroll
            for (int i = 0; i < 4; ++i) {
                int c = sseg * 4 + i;
                int slot = (c + srow) & 31;
                *(uint4*)(dst + i * 8) = *(const uint4*)(hE + srow * 512 + slot * 16);
            }
        }
    }
}

// ---------------- generic bf16 GEMM (A[M][K] @ BT[N][K]) -> f32 or bf16 C ----------------
__global__ __launch_bounds__(256)
void gemm_bf16(const u16* __restrict__ A, long long sAz,
               const u16* __restrict__ BT, long long sBz,
               void* __restrict__ Craw, long long sCz,
               const float* __restrict__ bias, int K, int obf) {
    __shared__ u16 As[128 * LDK];
    __shared__ u16 Bs[128 * LDK];
    const int z = blockIdx.z;
    A += z * sAz; BT += z * sBz;
    const int N = gridDim.y * 128;
    const int bm0 = blockIdx.x * 128;
    const int bn0 = blockIdx.y * 128;
    const int tid = threadIdx.x;
    const int l = tid & 63;
    const int wave = tid >> 6;
    const int wrow = (wave >> 1) * 64;
    const int wcol = (wave & 1) * 64;

    const u16* srcA[4]; const u16* srcB[4]; u16* dstA[4]; u16* dstB[4];
#pragma unroll
    for (int i = 0; i < 4; ++i) {
        int idx = i * 256 + tid;
        int row = idx >> 3;
        int kE = (idx & 7) * 8;
        srcA[i] = A + (long long)(bm0 + row) * K + kE;
        srcB[i] = BT + (long long)(bn0 + row) * K + kE;
        dstA[i] = As + row * LDK + kE;
        dstB[i] = Bs + row * LDK + kE;
    }
    f32x4 acc[4][4];
    const f32x4 zz = {0.f, 0.f, 0.f, 0.f};
#pragma unroll
    for (int m = 0; m < 4; ++m)
#pragma unroll
        for (int n = 0; n < 4; ++n) acc[m][n] = zz;

    for (int kk = 0; kk < K; kk += 64) {
#pragma unroll
        for (int i = 0; i < 4; ++i) {
            *(uint4*)dstA[i] = *(const uint4*)(srcA[i] + kk);
            *(uint4*)dstB[i] = *(const uint4*)(srcB[i] + kk);
        }
        __syncthreads();
        const int lro = l & 15;
        const int lk = (l >> 4) * 8;
#pragma unroll
        for (int k2 = 0; k2 < 64; k2 += 32) {
            bf16x8 av[4], bv[4];
#pragma unroll
            for (int m = 0; m < 4; ++m)
                av[m] = *(const bf16x8*)(As + (wrow + m * 16 + lro) * LDK + k2 + lk);
#pragma unroll
            for (int n = 0; n < 4; ++n)
                bv[n] = *(const bf16x8*)(Bs + (wcol + n * 16 + lro) * LDK + k2 + lk);
#pragma unroll
            for (int m = 0; m < 4; ++m)
#pragma unroll
                for (int n = 0; n < 4; ++n)
                    acc[m][n] = __builtin_amdgcn_mfma_f32_16x16x32_bf16(av[m], bv[n], acc[m][n], 0, 0, 0);
        }
        __syncthreads();
    }
#pragma unroll
    for (int m = 0; m < 4; ++m)
#pragma unroll
        for (int n = 0; n < 4; ++n) {
            int Cg = bn0 + wcol + n * 16 + (l & 15);
            float bv = bias ? bias[Cg] : 0.f;
#pragma unroll
            for (int r = 0; r < 4; ++r) {
                int R = bm0 + wrow + m * 16 + (l >> 4) * 4 + r;
                float v = acc[m][n][r] + bv;
                if (obf) ((u16*)Craw)[z * sCz + (long long)R * N + Cg] = f2bf(v);
                else     ((float*)Craw)[z * sCz + (long long)R * N + Cg] = v;
            }
        }
}

// ---------------- final per-level combine (permuted space, scatter to original) ----------------
__global__ void combine_level(const u16* __restrict__ G0, const u16* __restrict__ G13,
                              const u16* __restrict__ Wx, const int* __restrict__ ind,
                              const int* __restrict__ perm, const float* __restrict__ cprev,
                              float* __restrict__ outH, float* __restrict__ outC,
                              u16* __restrict__ hnext, float* __restrict__ cnext) {
    int i = blockIdx.x;
    int orig = perm[i];
    int j = threadIdx.x;
    float wf = bf2f(Wx[i * 1024 + j]);          // split order f,i,u,o
    float wi = bf2f(Wx[i * 1024 + 256 + j]);
    float wu = bf2f(Wx[i * 1024 + 512 + j]);
    float wo = bf2f(Wx[i * 1024 + 768 + j]);
    float bfa = 0.f;
#pragma unroll
    for (int k = 0; k < 8; ++k) {
        int iv = ind[orig * 8 + k];
        if (iv == -1) continue;
        float cc = (iv >= 1) ? cprev[(iv - 1) * 256 + j] : 0.f;
        bfa += sigm(wf + bf2f(G0[(i * 8 + k) * 256 + j])) * cc;
    }
    float bi = sigm(bf2f(G13[0 * NN * 256 + i * 256 + j]) + wi);
    float bu = tanh_(bf2f(G13[1 * NN * 256 + i * 256 + j]) + wu);
    float bo = sigm(bf2f(G13[2 * NN * 256 + i * 256 + j]) + wo);
    float nc = bi * bu + bfa;
    float nh = bo * tanh_(nc);
    outH[orig * 256 + j] = nh;
    outC[orig * 256 + j] = nc;
    hnext[orig * 256 + j] = f2bf(nh);
    cnext[orig * 256 + j] = nc;
}

extern "C" void kernel_launch(void* const* d_in, const int* in_sizes, int n_in,
                              void* d_out, int out_size, void* d_ws, size_t ws_size,
                              hipStream_t stream) {
    (void)in_sizes; (void)n_in; (void)out_size; (void)ws_size;
    const float* tensor  = (const float*)d_in[0];
    const int*   indices = (const int*)d_in[1];
    const float* Wk      = (const float*)d_in[2];
    const float* Wb      = (const float*)d_in[3];
    const float* kf      = (const float*)d_in[4];
    const float* rf      = (const float*)d_in[5];
    const float* bfw     = (const float*)d_in[6];
    const float* kb      = (const float*)d_in[7];
    const float* rb      = (const float*)d_in[8];
    const float* bbw     = (const float*)d_in[9];
    const float* ihf     = (const float*)d_in[10];
    const float* icf     = (const float*)d_in[11];
    const float* ihb     = (const float*)d_in[12];
    const float* icb     = (const float*)d_in[13];
    const float* fck     = (const float*)d_in[14];
    float* out = (float*)d_out;

    char* p = (char*)d_ws;
    auto take = [&](size_t bytes) -> char* {
        char* r = p;
        p += (bytes + 255) & ~(size_t)255;
        return r;
    };
    u16*   W2        = (u16*)  take(8ull * 1024 * 512 * 2);
    float* biasP     = (float*)take(8ull * 1024 * 4);
    u16*   WkT       = (u16*)  take(1024ull * 256 * 2);
    u16*   fcT       = (u16*)  take(4ull * 256 * 512 * 2);
    u16*   h0c       = (u16*)  take(8ull * 256 * 2);
    float* c0c       = (float*)take(8ull * 256 * 4);
    int*   perm      = (int*)  take((size_t)NLVL * NN * 4);
    int*   len_all   = (int*)  take((size_t)NLVL * NN * 4);
    int*   len_p     = (int*)  take((size_t)NLVL * NN * 4);
    int*   hist      = (int*)  take((size_t)NLVL * 8 * 4);
    u16*   Xbf       = (u16*)  take((size_t)NN * 256 * 2);
    u16*   Hc        = (u16*)  take((size_t)NN * 8 * 256 * 2);
    u16*   Y0        = (u16*)  take((size_t)NN * 8 * 512 * 2);
    u16*   ylast     = (u16*)  take(3ull * NN * 512 * 2);
    u16*   Wx        = (u16*)  take((size_t)NN * 1024 * 2);
    u16*   G0        = (u16*)  take((size_t)NN * 8 * 256 * 2);
    u16*   G13       = (u16*)  take(3ull * NN * 256 * 2);
    u16*   hprev[2]  = { (u16*)take((size_t)NN * 256 * 2), (u16*)take((size_t)NN * 256 * 2) };
    float* cprev[2]  = { (float*)take((size_t)NN * 256 * 4), (float*)take((size_t)NN * 256 * 4) };

    // one-time packing + length sort
    hipMemsetAsync(hist, 0, (size_t)NLVL * 8 * 4, stream);
    pack_wcomb<<<dim3(1024, 8), 256, 0, stream>>>(kf, rf, kb, rb, bfw, bbw, W2, biasP);
    pack_fcT<<<dim3(256, 4), 256, 0, stream>>>(fck, fcT);
    pack_wkT<<<dim3(1024), 256, 0, stream>>>(Wk, WkT);
    pack_init<<<dim3(8), 256, 0, stream>>>(ihf, icf, ihb, icb, h0c, c0c);
    compute_len<<<dim3(32, NLVL), 128, 0, stream>>>(indices, len_all, hist);
    build_perm<<<dim3(NLVL), 256, 0, stream>>>(len_all, hist, perm, len_p);

    for (int lvl = 0; lvl < NLVL; ++lvl) {
        const int* ind = indices + (size_t)lvl * NN * 8;
        const int* permL = perm + (size_t)lvl * NN;
        const int* lenpL = len_p + (size_t)lvl * NN;
        int cur = lvl & 1, nxt = cur ^ 1;

        convert_x<<<dim3(NN), 256, 0, stream>>>(tensor + (size_t)lvl * NN * 256, permL, Xbf);
        gather_children<<<dim3(NN), 256, 0, stream>>>(ind, permL, hprev[cur], Hc);

        // Wx = X @ W_kernel + W_bias   (M=4096, N=1024, K=256), permuted rows -> bf16
        gemm_bf16<<<dim3(32, 8, 1), 256, 0, stream>>>(Xbf, 0, WkT, 0, Wx, 0, Wb, 256, 1);

        // all recurrent steps, fused + persistent
        lstm_persist<<<dim3(512), 512, 0, stream>>>(Hc, W2, biasP, h0c, c0c, lenpL, Y0, ylast);

        // gate0 fc: [N*8, 512] @ fc0 -> G0 bf16   (M=32768, N=256, K=512)
        gemm_bf16<<<dim3(256, 2, 1), 256, 0, stream>>>(Y0, 0, fcT, 0, G0, 0, nullptr, 512, 1);
        // gates 1..3 fc: [N, 512] @ fc[g] -> G13[g-1] bf16   (batched over z)
        gemm_bf16<<<dim3(32, 2, 3), 256, 0, stream>>>(
            ylast, (long long)NN * 512, fcT + 256 * 512, (long long)256 * 512,
            G13, (long long)NN * 256, nullptr, 512, 1);

        combine_level<<<dim3(NN), 256, 0, stream>>>(
            G0, G13, Wx, ind, permL, cprev[cur],
            out + (size_t)lvl * NN * 256,
            out + (size_t)NLVL * NN * 256 + (size_t)lvl * NN * 256,
            hprev[nxt], cprev[nxt]);
    }
}

// Round 13
// 3544.073 us; speedup vs baseline: 2.2857x; 2.2857x over previous
//
#include <hip/hip_runtime.h>

typedef unsigned short u16;
typedef float f32x4 __attribute__((ext_vector_type(4)));
typedef __bf16 bf16x8 __attribute__((ext_vector_type(8)));

#define NN   4096
#define NLVL 6
#define LDK  72   // padded LDS k-stride for generic gemm only

static __device__ __forceinline__ u16 f2bf(float f) {
    unsigned int u = __float_as_uint(f);
    u += 0x7fffu + ((u >> 16) & 1u);
    return (u16)(u >> 16);
}
static __device__ __forceinline__ float bf2f(u16 v) {
    return __uint_as_float(((unsigned int)v) << 16);
}
static __device__ __forceinline__ float sigm(float x) { return 1.0f / (1.0f + __expf(-x)); }
static __device__ __forceinline__ float tanh_(float x) { return 2.0f / (1.0f + __expf(-2.0f * x)) - 1.0f; }

// ---------------- weight packing (once per launch) ----------------
// WcombT[chain][C][k] : C = 4*j + ig (gate-interleaved), k<256 -> K[k][ig*256+j], else R[k-256][..]
__global__ void pack_wcomb(const float* __restrict__ kf, const float* __restrict__ rf,
                           const float* __restrict__ kb, const float* __restrict__ rb,
                           const float* __restrict__ bfw, const float* __restrict__ bbw,
                           u16* __restrict__ WcombT, float* __restrict__ biasP) {
    int C = blockIdx.x, chain = blockIdx.y;
    int g = chain >> 1, dir = chain & 1;
    int ig = C & 3, j = C >> 2;
    int oc = ig * 256 + j;
    const float* Ks = (dir ? kb : kf) + g * (256 * 1024);
    const float* Rs = (dir ? rb : rf) + g * (256 * 1024);
    u16* dst = WcombT + (chain * 1024 + C) * 512;
    for (int it = 0; it < 2; ++it) {
        int k = it * 256 + threadIdx.x;
        float v = (k < 256) ? Ks[k * 1024 + oc] : Rs[(k - 256) * 1024 + oc];
        dst[k] = f2bf(v);
    }
    if (threadIdx.x == 0) biasP[chain * 1024 + C] = (dir ? bbw : bfw)[g * 1024 + oc];
}

// fcT[g][n][k] = fc[g][k][n]
__global__ void pack_fcT(const float* __restrict__ fck, u16* __restrict__ fcT) {
    int n = blockIdx.x, g = blockIdx.y;
    u16* dst = fcT + (g * 256 + n) * 512;
    for (int it = 0; it < 2; ++it) {
        int k = it * 256 + threadIdx.x;
        dst[k] = f2bf(fck[(g * 512 + k) * 256 + n]);
    }
}

// WkT[C][k] = W_kernel[k][C]
__global__ void pack_wkT(const float* __restrict__ Wk, u16* __restrict__ WkT) {
    int C = blockIdx.x;
    int k = threadIdx.x;
    WkT[C * 256 + k] = f2bf(Wk[k * 1024 + C]);
}

// h0c[chain][256] bf16, c0c[chain][256] f32 broadcast-init vectors
__global__ void pack_init(const float* __restrict__ ihf, const float* __restrict__ icf,
                          const float* __restrict__ ihb, const float* __restrict__ icb,
                          u16* __restrict__ h0c, float* __restrict__ c0c) {
    int chain = blockIdx.x, j = threadIdx.x;
    int g = chain >> 1, dir = chain & 1;
    h0c[chain * 256 + j] = f2bf((dir ? ihb : ihf)[g * 256 + j]);
    c0c[chain * 256 + j] = (dir ? icb : icf)[g * 256 + j];
}

// ---------------- length histogram + counting sort (once) ----------------
__global__ void compute_len(const int* __restrict__ indices, int* __restrict__ len_all,
                            int* __restrict__ hist) {
    int lvl = blockIdx.y;
    int b = blockIdx.x * 128 + threadIdx.x;
    const int* ind = indices + ((size_t)lvl * NN + b) * 8;
    int len = 0;
#pragma unroll
    for (int k = 0; k < 8; ++k) len += (ind[k] != -1) ? 1 : 0;
    len_all[lvl * NN + b] = len;
    atomicAdd(&hist[lvl * 8 + (len - 1)], 1);
}

// descending-length counting sort: perm[i] = original node, len_p sorted
__global__ void build_perm(const int* __restrict__ len_all, const int* __restrict__ hist,
                           int* __restrict__ perm, int* __restrict__ len_p) {
    int lvl = blockIdx.x;
    __shared__ int off[9];
    __shared__ int cur[9];
    if (threadIdx.x == 0) {
        int s = 0;
        for (int L = 8; L >= 1; --L) { off[L] = s; cur[L] = 0; s += hist[lvl * 8 + L - 1]; }
    }
    __syncthreads();
    for (int b = threadIdx.x; b < NN; b += blockDim.x) {
        int len = len_all[lvl * NN + b];
        int pos = off[len] + atomicAdd(&cur[len], 1);
        perm[lvl * NN + pos] = b;
        len_p[lvl * NN + pos] = len;
    }
}

// ---------------- per-level prep (all in permuted row space) ----------------
__global__ void convert_x(const float* __restrict__ x, const int* __restrict__ perm,
                          u16* __restrict__ xb) {
    int i = blockIdx.x;
    int orig = perm[i];
    xb[i * 256 + threadIdx.x] = f2bf(x[orig * 256 + threadIdx.x]);
}

__global__ void gather_children(const int* __restrict__ ind, const int* __restrict__ perm,
                                const u16* __restrict__ h_prev, u16* __restrict__ Hc) {
    int i = blockIdx.x;
    int orig = perm[i];
    int k = threadIdx.x >> 5;
    int c0 = (threadIdx.x & 31) * 8;
    int iv = ind[orig * 8 + k];
    uint4 v = make_uint4(0u, 0u, 0u, 0u);
    if (iv >= 1) v = *(const uint4*)(h_prev + (iv - 1) * 256 + c0);
    *(uint4*)(Hc + (i * 8 + k) * 256 + c0) = v;
}

// ---------------- persistent fused BiLSTM v8 = round-5 structure + conflict-free LDS ----------------
// 512 blocks x 512 threads; chain = bid&7 (XCD-pinned), 64-row batch tile.
// Weights: round-5's 3-buffer LDS pipeline (16KB stages, 1 barrier/stage) - the ONLY
//   variant measured spill-free (VGPR 92, WRITE 96MB). Byte-identical here.
// B (x,h): ROTATED layout (r10-12, verified): 512B rows, 16B-chunk slot=(chunk+row)&31
//   -> B-reads at the 8-cycle b128 minimum; h-scatter = paired-shfl u32 writes (2-way, free).
// Wave = 32 C-rows (crow0) x 32 batch cols (bcol0); 64 stages/t cover 1024 C x 512 K.
__global__ __launch_bounds__(512)
void lstm_persist(const u16* __restrict__ Hc,
                  const u16* __restrict__ WcombT, const float* __restrict__ biasP,
                  const u16* __restrict__ h0c, const float* __restrict__ c0c,
                  const int* __restrict__ len_p,
                  u16* __restrict__ Y0, u16* __restrict__ ylast) {
    __shared__ __align__(16) u16 xS[64 * 256];      // 32 KB, 512B rows, rotated chunks
    __shared__ __align__(16) u16 hS[64 * 256];      // 32 KB
    __shared__ __align__(16) u16 aS[3][128 * 72];   // 3 x 18 KB, 144B rows (64k + pad)
    const int bid = blockIdx.x;
    const int chain = bid & 7;
    const int bi0 = (bid >> 3) * 64;
    const int dir = chain & 1;
    const int tid = threadIdx.x;
    const int l = tid & 63;
    const int wave = tid >> 6;
    const int wC = wave >> 1;            // 0..3: 32-row C-group within 128-row tile
    const int wB = wave & 1;             // 0..1: 32-col batch half
    const int crow0 = wC * 32;
    const int bcol0 = wB * 32;
    const int lro = l & 15;
    const int q4 = l >> 4;

    const int maxlen = len_p[bi0];       // sorted descending
    const int srow = tid >> 3;           // x/h staging + emit row 0..63
    const int sseg = tid & 7;            // 4 chunks of 16B
    const int slen = len_p[bi0 + srow];
    const int wrow = tid >> 2;           // weight staging row 0..127
    const int wseg = tid & 3;            // 32B segment

    const u16* Wc = WcombT + (size_t)chain * (1024 * 512);
    char* xSc = (char*)xS;
    char* hSc = (char*)hS;

    // init hS = rotated h0 broadcast (visible via t=0 prologue barrier)
    {
        const u16* h0 = h0c + chain * 256;
#pragma unroll
        for (int i = 0; i < 4; ++i) {
            int c = sseg * 4 + i;
            int slot = (c + srow) & 31;
            *(uint4*)(hSc + srow * 512 + slot * 16) = *(const uint4*)(h0 + c * 8);
        }
    }
    // c state in regs: c_reg[cj][m*2+n], channel jj = cj*32 + wC*8 + m*4 + q4
    float c_reg[8][4];
#pragma unroll
    for (int cj = 0; cj < 8; ++cj)
#pragma unroll
        for (int m = 0; m < 2; ++m) {
            int jj = cj * 32 + wC * 8 + m * 4 + q4;
            float cv = c0c[chain * 256 + jj];
            c_reg[cj][m * 2 + 0] = cv;
            c_reg[cj][m * 2 + 1] = cv;
        }
    unsigned int hp[8][2];               // pending h, [cj][m]: n=0,1 packed in one u32
    const f32x4 zz = {0.f, 0.f, 0.f, 0.f};

    for (int t = 0; t < maxlen; ++t) {
        // ---- stage x tile (rotated; prior xS readers finished at last stage barrier) ----
        {
            int ts = dir ? (slen - 1 - t) : t;
            ts = ts < 0 ? 0 : (ts > 7 ? 7 : ts);
            const u16* src = Hc + ((size_t)(bi0 + srow) * 8 + ts) * 256;
#pragma unroll
            for (int i = 0; i < 4; ++i) {
                int c = sseg * 4 + i;
                int slot = (c + srow) & 31;
                *(uint4*)(xSc + srow * 512 + slot * 16) = *(const uint4*)(src + c * 8);
            }
        }
        // ---- weight pipeline prologue: aS[0]<-s0, aS[1]<-s1, pf[0]<-s2 ----
        uint4 pfA[2], pfB[2];
        {
            const u16* s0 = Wc + (size_t)wrow * 512 + wseg * 16;
            uint4 a0 = *(const uint4*)s0, b0 = *(const uint4*)(s0 + 8);
            uint4 a1 = *(const uint4*)(s0 + 64), b1 = *(const uint4*)(s0 + 72);
            pfA[0] = *(const uint4*)(s0 + 128); pfB[0] = *(const uint4*)(s0 + 136);
            char* d0 = (char*)aS[0] + wrow * 144 + wseg * 32;
            *(uint4*)d0 = a0; *(uint4*)(d0 + 16) = b0;
            char* d1 = (char*)aS[1] + wrow * 144 + wseg * 32;
            *(uint4*)d1 = a1; *(uint4*)(d1 + 16) = b1;
        }
        __syncthreads();

        f32x4 acc[2][2];
#pragma unroll
        for (int it = 0; it < 64; ++it) {
            const int cj = it >> 3, kt = it & 7;
            if (kt == 0) { acc[0][0] = zz; acc[0][1] = zz; acc[1][0] = zz; acc[1][1] = zz; }
            // issue global prefetch of W(it+3)
            if (it + 3 < 64) {
                int nit = it + 3;
                const u16* s = Wc + (size_t)(((nit >> 3) * 128 + wrow) * 512 + (nit & 7) * 64 + wseg * 16);
                pfA[(it + 1) & 1] = *(const uint4*)s;
                pfB[(it + 1) & 1] = *(const uint4*)(s + 8);
            }
            const char* aB = (const char*)aS[it % 3];
            const char* bB = (kt < 4) ? xSc : hSc;
#pragma unroll
            for (int ks = 0; ks < 2; ++ks) {
                bf16x8 av[2], bv[2];
#pragma unroll
                for (int m = 0; m < 2; ++m) {
                    int r = crow0 + m * 16 + lro;
                    av[m] = *(const bf16x8*)(aB + r * 144 + ks * 64 + q4 * 16);
                }
                const int cb = (kt & 3) * 8 + ks * 4 + q4;   // 16B chunk within 512B row
#pragma unroll
                for (int n = 0; n < 2; ++n) {
                    int row = bcol0 + n * 16 + lro;
                    int slot = (cb + row) & 31;
                    bv[n] = *(const bf16x8*)(bB + row * 512 + slot * 16);
                }
#pragma unroll
                for (int m = 0; m < 2; ++m)
#pragma unroll
                    for (int n = 0; n < 2; ++n)
                        acc[m][n] = __builtin_amdgcn_mfma_f32_16x16x32_bf16(av[m], bv[n], acc[m][n], 0, 0, 0);
            }
            // cell epilogue after K complete for this cj (pure VALU)
            if (kt == 7) {
#pragma unroll
                for (int m = 0; m < 2; ++m) {
                    int Crow = cj * 128 + crow0 + m * 16 + q4 * 4;
                    float4 bias = *(const float4*)(biasP + chain * 1024 + Crow);
                    unsigned int packed = 0;
#pragma unroll
                    for (int n = 0; n < 2; ++n) {
                        float zi = acc[m][n][0] + bias.x;
                        float zf = acc[m][n][1] + bias.y;
                        float zg = acc[m][n][2] + bias.z;
                        float zo = acc[m][n][3] + bias.w;
                        float cn = sigm(zf) * c_reg[cj][m * 2 + n] + sigm(zi) * tanh_(zg);
                        float hn = sigm(zo) * tanh_(cn);
                        c_reg[cj][m * 2 + n] = cn;
                        packed |= ((unsigned int)f2bf(hn)) << (16 * n);
                    }
                    hp[cj][m] = packed;
                }
            }
            __syncthreads();
            // write next weight buffer (data prefetched last iter)
            if (it + 2 < 64) {
                char* d = (char*)aS[(it + 2) % 3] + wrow * 144 + wseg * 32;
                *(uint4*)d = pfA[it & 1];
                *(uint4*)(d + 16) = pfB[it & 1];
            }
        }
        __syncthreads();                 // all hS/xS reads of this step done

        // ---- h-state scatter: paired shfl -> u32 writes, 2-way banks (free) ----
#pragma unroll
        for (int cj = 0; cj < 8; ++cj)
#pragma unroll
            for (int m = 0; m < 2; ++m) {
                int chunk = cj * 4 + wC;             // = jj>>3 (m*4+q4 <= 7)
                int jb = (m * 4 + q4) * 2;           // byte offset within 16B chunk
#pragma unroll
                for (int n = 0; n < 2; ++n) {
                    unsigned int val = (hp[cj][m] >> (16 * n)) & 0xffffu;
                    unsigned int other = (unsigned int)__shfl_xor((int)val, 16);
                    if ((q4 & 1) == 0) {             // even q4 -> even jj -> 4B aligned
                        int bl = bcol0 + n * 16 + lro;
                        int slot = (chunk + bl) & 31;
                        *(unsigned int*)(hSc + bl * 512 + slot * 16 + jb) = val | (other << 16);
                    }
                }
            }
        __syncthreads();                 // new h visible

        // ---- coalesced global outputs from hS (rotated) ----
        if (chain < 2) {
            u16* dst = Y0 + ((size_t)(bi0 + srow) * 8 + t) * 512 + dir * 256 + sseg * 32;
#pragma unroll
            for (int i = 0; i < 4; ++i) {
                int c = sseg * 4 + i;
                int slot = (c + srow) & 31;
                *(uint4*)(dst + i * 8) = *(const uint4*)(hSc + srow * 512 + slot * 16);
            }
        } else if (t == slen - 1) {
            u16* dst = ylast + (size_t)((chain >> 1) - 1) * (NN * 512)
                     + (size_t)(bi0 + srow) * 512 + dir * 256 + sseg * 32;
#pragma unroll
            for (int i = 0; i < 4; ++i) {
                int c = sseg * 4 + i;
                int slot = (c + srow) & 31;
                *(uint4*)(dst + i * 8) = *(const uint4*)(hSc + srow * 512 + slot * 16);
            }
        }
        // next t's xS stage / aS prologue touch buffers whose readers finished above
    }
}

// ---------------- generic bf16 GEMM (A[M][K] @ BT[N][K]) -> f32 or bf16 C ----------------
__global__ __launch_bounds__(256)
void gemm_bf16(const u16* __restrict__ A, long long sAz,
               const u16* __restrict__ BT, long long sBz,
               void* __restrict__ Craw, long long sCz,
               const float* __restrict__ bias, int K, int obf) {
    __shared__ u16 As[128 * LDK];
    __shared__ u16 Bs[128 * LDK];
    const int z = blockIdx.z;
    A += z * sAz; BT += z * sBz;
    const int N = gridDim.y * 128;
    const int bm0 = blockIdx.x * 128;
    const int bn0 = blockIdx.y * 128;
    const int tid = threadIdx.x;
    const int l = tid & 63;
    const int wave = tid >> 6;
    const int wrow = (wave >> 1) * 64;
    const int wcol = (wave & 1) * 64;

    const u16* srcA[4]; const u16* srcB[4]; u16* dstA[4]; u16* dstB[4];
#pragma unroll
    for (int i = 0; i < 4; ++i) {
        int idx = i * 256 + tid;
        int row = idx >> 3;
        int kE = (idx & 7) * 8;
        srcA[i] = A + (long long)(bm0 + row) * K + kE;
        srcB[i] = BT + (long long)(bn0 + row) * K + kE;
        dstA[i] = As + row * LDK + kE;
        dstB[i] = Bs + row * LDK + kE;
    }
    f32x4 acc[4][4];
    const f32x4 zz = {0.f, 0.f, 0.f, 0.f};
#pragma unroll
    for (int m = 0; m < 4; ++m)
#pragma unroll
        for (int n = 0; n < 4; ++n) acc[m][n] = zz;

    for (int kk = 0; kk < K; kk += 64) {
#pragma unroll
        for (int i = 0; i < 4; ++i) {
            *(uint4*)dstA[i] = *(const uint4*)(srcA[i] + kk);
            *(uint4*)dstB[i] = *(const uint4*)(srcB[i] + kk);
        }
        __syncthreads();
        const int lro = l & 15;
        const int lk = (l >> 4) * 8;
#pragma unroll
        for (int k2 = 0; k2 < 64; k2 += 32) {
            bf16x8 av[4], bv[4];
#pragma unroll
            for (int m = 0; m < 4; ++m)
                av[m] = *(const bf16x8*)(As + (wrow + m * 16 + lro) * LDK + k2 + lk);
#pragma unroll
            for (int n = 0; n < 4; ++n)
                bv[n] = *(const bf16x8*)(Bs + (wcol + n * 16 + lro) * LDK + k2 + lk);
#pragma unroll
            for (int m = 0; m < 4; ++m)
#pragma unroll
                for (int n = 0; n < 4; ++n)
                    acc[m][n] = __builtin_amdgcn_mfma_f32_16x16x32_bf16(av[m], bv[n], acc[m][n], 0, 0, 0);
        }
        __syncthreads();
    }
#pragma unroll
    for (int m = 0; m < 4; ++m)
#pragma unroll
        for (int n = 0; n < 4; ++n) {
            int Cg = bn0 + wcol + n * 16 + (l & 15);
            float bv = bias ? bias[Cg] : 0.f;
#pragma unroll
            for (int r = 0; r < 4; ++r) {
                int R = bm0 + wrow + m * 16 + (l >> 4) * 4 + r;
                float v = acc[m][n][r] + bv;
                if (obf) ((u16*)Craw)[z * sCz + (long long)R * N + Cg] = f2bf(v);
                else     ((float*)Craw)[z * sCz + (long long)R * N + Cg] = v;
            }
        }
}

// ---------------- final per-level combine (permuted space, scatter to original) ----------------
__global__ void combine_level(const u16* __restrict__ G0, const u16* __restrict__ G13,
                              const u16* __restrict__ Wx, const int* __restrict__ ind,
                              const int* __restrict__ perm, const float* __restrict__ cprev,
                              float* __restrict__ outH, float* __restrict__ outC,
                              u16* __restrict__ hnext, float* __restrict__ cnext) {
    int i = blockIdx.x;
    int orig = perm[i];
    int j = threadIdx.x;
    float wf = bf2f(Wx[i * 1024 + j]);          // split order f,i,u,o
    float wi = bf2f(Wx[i * 1024 + 256 + j]);
    float wu = bf2f(Wx[i * 1024 + 512 + j]);
    float wo = bf2f(Wx[i * 1024 + 768 + j]);
    float bfa = 0.f;
#pragma unroll
    for (int k = 0; k < 8; ++k) {
        int iv = ind[orig * 8 + k];
        if (iv == -1) continue;
        float cc = (iv >= 1) ? cprev[(iv - 1) * 256 + j] : 0.f;
        bfa += sigm(wf + bf2f(G0[(i * 8 + k) * 256 + j])) * cc;
    }
    float bi = sigm(bf2f(G13[0 * NN * 256 + i * 256 + j]) + wi);
    float bu = tanh_(bf2f(G13[1 * NN * 256 + i * 256 + j]) + wu);
    float bo = sigm(bf2f(G13[2 * NN * 256 + i * 256 + j]) + wo);
    float nc = bi * bu + bfa;
    float nh = bo * tanh_(nc);
    outH[orig * 256 + j] = nh;
    outC[orig * 256 + j] = nc;
    hnext[orig * 256 + j] = f2bf(nh);
    cnext[orig * 256 + j] = nc;
}

extern "C" void kernel_launch(void* const* d_in, const int* in_sizes, int n_in,
                              void* d_out, int out_size, void* d_ws, size_t ws_size,
                              hipStream_t stream) {
    (void)in_sizes; (void)n_in; (void)out_size; (void)ws_size;
    const float* tensor  = (const float*)d_in[0];
    const int*   indices = (const int*)d_in[1];
    const float* Wk      = (const float*)d_in[2];
    const float* Wb      = (const float*)d_in[3];
    const float* kf      = (const float*)d_in[4];
    const float* rf      = (const float*)d_in[5];
    const float* bfw     = (const float*)d_in[6];
    const float* kb      = (const float*)d_in[7];
    const float* rb      = (const float*)d_in[8];
    const float* bbw     = (const float*)d_in[9];
    const float* ihf     = (const float*)d_in[10];
    const float* icf     = (const float*)d_in[11];
    const float* ihb     = (const float*)d_in[12];
    const float* icb     = (const float*)d_in[13];
    const float* fck     = (const float*)d_in[14];
    float* out = (float*)d_out;

    char* p = (char*)d_ws;
    auto take = [&](size_t bytes) -> char* {
        char* r = p;
        p += (bytes + 255) & ~(size_t)255;
        return r;
    };
    u16*   WcombT    = (u16*)  take(8ull * 1024 * 512 * 2);
    float* biasP     = (float*)take(8ull * 1024 * 4);
    u16*   WkT       = (u16*)  take(1024ull * 256 * 2);
    u16*   fcT       = (u16*)  take(4ull * 256 * 512 * 2);
    u16*   h0c       = (u16*)  take(8ull * 256 * 2);
    float* c0c       = (float*)take(8ull * 256 * 4);
    int*   perm      = (int*)  take((size_t)NLVL * NN * 4);
    int*   len_all   = (int*)  take((size_t)NLVL * NN * 4);
    int*   len_p     = (int*)  take((size_t)NLVL * NN * 4);
    int*   hist      = (int*)  take((size_t)NLVL * 8 * 4);
    u16*   Xbf       = (u16*)  take((size_t)NN * 256 * 2);
    u16*   Hc        = (u16*)  take((size_t)NN * 8 * 256 * 2);
    u16*   Y0        = (u16*)  take((size_t)NN * 8 * 512 * 2);
    u16*   ylast     = (u16*)  take(3ull * NN * 512 * 2);
    u16*   Wx        = (u16*)  take((size_t)NN * 1024 * 2);
    u16*   G0        = (u16*)  take((size_t)NN * 8 * 256 * 2);
    u16*   G13       = (u16*)  take(3ull * NN * 256 * 2);
    u16*   hprev[2]  = { (u16*)take((size_t)NN * 256 * 2), (u16*)take((size_t)NN * 256 * 2) };
    float* cprev[2]  = { (float*)take((size_t)NN * 256 * 4), (float*)take((size_t)NN * 256 * 4) };

    // one-time packing + length sort
    hipMemsetAsync(hist, 0, (size_t)NLVL * 8 * 4, stream);
    pack_wcomb<<<dim3(1024, 8), 256, 0, stream>>>(kf, rf, kb, rb, bfw, bbw, WcombT, biasP);
    pack_fcT<<<dim3(256, 4), 256, 0, stream>>>(fck, fcT);
    pack_wkT<<<dim3(1024), 256, 0, stream>>>(Wk, WkT);
    pack_init<<<dim3(8), 256, 0, stream>>>(ihf, icf, ihb, icb, h0c, c0c);
    compute_len<<<dim3(32, NLVL), 128, 0, stream>>>(indices, len_all, hist);
    build_perm<<<dim3(NLVL), 256, 0, stream>>>(len_all, hist, perm, len_p);

    for (int lvl = 0; lvl < NLVL; ++lvl) {
        const int* ind = indices + (size_t)lvl * NN * 8;
        const int* permL = perm + (size_t)lvl * NN;
        const int* lenpL = len_p + (size_t)lvl * NN;
        int cur = lvl & 1, nxt = cur ^ 1;

        convert_x<<<dim3(NN), 256, 0, stream>>>(tensor + (size_t)lvl * NN * 256, permL, Xbf);
        gather_children<<<dim3(NN), 256, 0, stream>>>(ind, permL, hprev[cur], Hc);

        // Wx = X @ W_kernel + W_bias   (M=4096, N=1024, K=256), permuted rows -> bf16
        gemm_bf16<<<dim3(32, 8, 1), 256, 0, stream>>>(Xbf, 0, WkT, 0, Wx, 0, Wb, 256, 1);

        // all recurrent steps, fused + persistent
        lstm_persist<<<dim3(512), 512, 0, stream>>>(Hc, WcombT, biasP, h0c, c0c, lenpL, Y0, ylast);

        // gate0 fc: [N*8, 512] @ fc0 -> G0 bf16   (M=32768, N=256, K=512)
        gemm_bf16<<<dim3(256, 2, 1), 256, 0, stream>>>(Y0, 0, fcT, 0, G0, 0, nullptr, 512, 1);
        // gates 1..3 fc: [N, 512] @ fc[g] -> G13[g-1] bf16   (batched over z)
        gemm_bf16<<<dim3(32, 2, 3), 256, 0, stream>>>(
            ylast, (long long)NN * 512, fcT + 256 * 512, (long long)256 * 512,
            G13, (long long)NN * 256, nullptr, 512, 1);

        combine_level<<<dim3(NN), 256, 0, stream>>>(
            G0, G13, Wx, ind, permL, cprev[cur],
            out + (size_t)lvl * NN * 256,
            out + (size_t)NLVL * NN * 256 + (size_t)lvl * NN * 256,
            hprev[nxt], cprev[nxt]);
    }
}

// Round 14
// 3431.075 us; speedup vs baseline: 2.3609x; 1.0329x over previous
//
#include <hip/hip_runtime.h>

typedef unsigned short u16;
typedef float f32x4 __attribute__((ext_vector_type(4)));
typedef __bf16 bf16x8 __attribute__((ext_vector_type(8)));

#define NN   4096
#define NLVL 6
#define LDK  72   // padded LDS k-stride for generic gemm only

static __device__ __forceinline__ u16 f2bf(float f) {
    unsigned int u = __float_as_uint(f);
    u += 0x7fffu + ((u >> 16) & 1u);
    return (u16)(u >> 16);
}
static __device__ __forceinline__ float bf2f(u16 v) {
    return __uint_as_float(((unsigned int)v) << 16);
}
static __device__ __forceinline__ float sigm(float x) { return 1.0f / (1.0f + __expf(-x)); }
static __device__ __forceinline__ float tanh_(float x) { return 2.0f / (1.0f + __expf(-2.0f * x)) - 1.0f; }

// ---------------- weight packing (once per launch) ----------------
// WcombT[chain][C][k] : C = 4*j + ig (gate-interleaved), k<256 -> K[k][ig*256+j], else R[k-256][..]
__global__ void pack_wcomb(const float* __restrict__ kf, const float* __restrict__ rf,
                           const float* __restrict__ kb, const float* __restrict__ rb,
                           const float* __restrict__ bfw, const float* __restrict__ bbw,
                           u16* __restrict__ WcombT, float* __restrict__ biasP) {
    int C = blockIdx.x, chain = blockIdx.y;
    int g = chain >> 1, dir = chain & 1;
    int ig = C & 3, j = C >> 2;
    int oc = ig * 256 + j;
    const float* Ks = (dir ? kb : kf) + g * (256 * 1024);
    const float* Rs = (dir ? rb : rf) + g * (256 * 1024);
    u16* dst = WcombT + (chain * 1024 + C) * 512;
    for (int it = 0; it < 2; ++it) {
        int k = it * 256 + threadIdx.x;
        float v = (k < 256) ? Ks[k * 1024 + oc] : Rs[(k - 256) * 1024 + oc];
        dst[k] = f2bf(v);
    }
    if (threadIdx.x == 0) biasP[chain * 1024 + C] = (dir ? bbw : bfw)[g * 1024 + oc];
}

// fcT[g][n][k] = fc[g][k][n]
__global__ void pack_fcT(const float* __restrict__ fck, u16* __restrict__ fcT) {
    int n = blockIdx.x, g = blockIdx.y;
    u16* dst = fcT + (g * 256 + n) * 512;
    for (int it = 0; it < 2; ++it) {
        int k = it * 256 + threadIdx.x;
        dst[k] = f2bf(fck[(g * 512 + k) * 256 + n]);
    }
}

// WkT[C][k] = W_kernel[k][C]
__global__ void pack_wkT(const float* __restrict__ Wk, u16* __restrict__ WkT) {
    int C = blockIdx.x;
    int k = threadIdx.x;
    WkT[C * 256 + k] = f2bf(Wk[k * 1024 + C]);
}

// h0c[chain][256] bf16, c0c[chain][256] f32 broadcast-init vectors
__global__ void pack_init(const float* __restrict__ ihf, const float* __restrict__ icf,
                          const float* __restrict__ ihb, const float* __restrict__ icb,
                          u16* __restrict__ h0c, float* __restrict__ c0c) {
    int chain = blockIdx.x, j = threadIdx.x;
    int g = chain >> 1, dir = chain & 1;
    h0c[chain * 256 + j] = f2bf((dir ? ihb : ihf)[g * 256 + j]);
    c0c[chain * 256 + j] = (dir ? icb : icf)[g * 256 + j];
}

// ---------------- length histogram + counting sort (once) ----------------
__global__ void compute_len(const int* __restrict__ indices, int* __restrict__ len_all,
                            int* __restrict__ hist) {
    int lvl = blockIdx.y;
    int b = blockIdx.x * 128 + threadIdx.x;
    const int* ind = indices + ((size_t)lvl * NN + b) * 8;
    int len = 0;
#pragma unroll
    for (int k = 0; k < 8; ++k) len += (ind[k] != -1) ? 1 : 0;
    len_all[lvl * NN + b] = len;
    atomicAdd(&hist[lvl * 8 + (len - 1)], 1);
}

// descending-length counting sort: perm[i] = original node, len_p sorted
__global__ void build_perm(const int* __restrict__ len_all, const int* __restrict__ hist,
                           int* __restrict__ perm, int* __restrict__ len_p) {
    int lvl = blockIdx.x;
    __shared__ int off[9];
    __shared__ int cur[9];
    if (threadIdx.x == 0) {
        int s = 0;
        for (int L = 8; L >= 1; --L) { off[L] = s; cur[L] = 0; s += hist[lvl * 8 + L - 1]; }
    }
    __syncthreads();
    for (int b = threadIdx.x; b < NN; b += blockDim.x) {
        int len = len_all[lvl * NN + b];
        int pos = off[len] + atomicAdd(&cur[len], 1);
        perm[lvl * NN + pos] = b;
        len_p[lvl * NN + pos] = len;
    }
}

// ---------------- per-level prep (all in permuted row space) ----------------
__global__ void convert_x(const float* __restrict__ x, const int* __restrict__ perm,
                          u16* __restrict__ xb) {
    int i = blockIdx.x;
    int orig = perm[i];
    xb[i * 256 + threadIdx.x] = f2bf(x[orig * 256 + threadIdx.x]);
}

__global__ void gather_children(const int* __restrict__ ind, const int* __restrict__ perm,
                                const u16* __restrict__ h_prev, u16* __restrict__ Hc) {
    int i = blockIdx.x;
    int orig = perm[i];
    int k = threadIdx.x >> 5;
    int c0 = (threadIdx.x & 31) * 8;
    int iv = ind[orig * 8 + k];
    uint4 v = make_uint4(0u, 0u, 0u, 0u);
    if (iv >= 1) v = *(const uint4*)(h_prev + (iv - 1) * 256 + c0);
    *(uint4*)(Hc + (i * 8 + k) * 256 + c0) = v;
}

// ---------------- persistent fused BiLSTM v8.1 = v8 + phase-conflict-free staging ----------------
// 512 blocks x 512 threads; chain = bid&7 (XCD-pinned), 64-row batch tile.
// Weights: round-5's 3-buffer LDS pipeline (spill-free: VGPR 124). Byte-identical.
// B (x,h): rotated layout, 512B rows, slot=(chunk+row)&31. MFMA-side reads conflict-free.
// FIX vs v8: staging/emit chunk mapping c = i*8 + sseg (was sseg*4+i). Consecutive lanes
//   now cover consecutive chunks -> each 8-lane LDS phase hits 8 distinct bank-groups
//   (was 2 -> 4-way conflict on every x-stage write and emit read).
__global__ __launch_bounds__(512)
void lstm_persist(const u16* __restrict__ Hc,
                  const u16* __restrict__ WcombT, const float* __restrict__ biasP,
                  const u16* __restrict__ h0c, const float* __restrict__ c0c,
                  const int* __restrict__ len_p,
                  u16* __restrict__ Y0, u16* __restrict__ ylast) {
    __shared__ __align__(16) u16 xS[64 * 256];      // 32 KB, 512B rows, rotated chunks
    __shared__ __align__(16) u16 hS[64 * 256];      // 32 KB
    __shared__ __align__(16) u16 aS[3][128 * 72];   // 3 x 18 KB, 144B rows (64k + pad)
    const int bid = blockIdx.x;
    const int chain = bid & 7;
    const int bi0 = (bid >> 3) * 64;
    const int dir = chain & 1;
    const int tid = threadIdx.x;
    const int l = tid & 63;
    const int wave = tid >> 6;
    const int wC = wave >> 1;            // 0..3: 32-row C-group within 128-row tile
    const int wB = wave & 1;             // 0..1: 32-col batch half
    const int crow0 = wC * 32;
    const int bcol0 = wB * 32;
    const int lro = l & 15;
    const int q4 = l >> 4;

    const int maxlen = len_p[bi0];       // sorted descending
    const int srow = tid >> 3;           // x/h staging + emit row 0..63
    const int sseg = tid & 7;            // chunk sub-index (consecutive lanes = consecutive)
    const int slen = len_p[bi0 + srow];
    const int wrow = tid >> 2;           // weight staging row 0..127
    const int wseg = tid & 3;            // 32B segment

    const u16* Wc = WcombT + (size_t)chain * (1024 * 512);
    char* xSc = (char*)xS;
    char* hSc = (char*)hS;

    // init hS = rotated h0 broadcast (visible via t=0 prologue barrier)
    {
        const u16* h0 = h0c + chain * 256;
#pragma unroll
        for (int i = 0; i < 4; ++i) {
            int c = i * 8 + sseg;
            int slot = (c + srow) & 31;
            *(uint4*)(hSc + srow * 512 + slot * 16) = *(const uint4*)(h0 + c * 8);
        }
    }
    // c state in regs: c_reg[cj][m*2+n], channel jj = cj*32 + wC*8 + m*4 + q4
    float c_reg[8][4];
#pragma unroll
    for (int cj = 0; cj < 8; ++cj)
#pragma unroll
        for (int m = 0; m < 2; ++m) {
            int jj = cj * 32 + wC * 8 + m * 4 + q4;
            float cv = c0c[chain * 256 + jj];
            c_reg[cj][m * 2 + 0] = cv;
            c_reg[cj][m * 2 + 1] = cv;
        }
    unsigned int hp[8][2];               // pending h, [cj][m]: n=0,1 packed in one u32
    const f32x4 zz = {0.f, 0.f, 0.f, 0.f};

    for (int t = 0; t < maxlen; ++t) {
        // ---- stage x tile (rotated; prior xS readers finished at last stage barrier) ----
        {
            int ts = dir ? (slen - 1 - t) : t;
            ts = ts < 0 ? 0 : (ts > 7 ? 7 : ts);
            const u16* src = Hc + ((size_t)(bi0 + srow) * 8 + ts) * 256;
#pragma unroll
            for (int i = 0; i < 4; ++i) {
                int c = i * 8 + sseg;
                int slot = (c + srow) & 31;
                *(uint4*)(xSc + srow * 512 + slot * 16) = *(const uint4*)(src + c * 8);
            }
        }
        // ---- weight pipeline prologue: aS[0]<-s0, aS[1]<-s1, pf[0]<-s2 ----
        uint4 pfA[2], pfB[2];
        {
            const u16* s0 = Wc + (size_t)wrow * 512 + wseg * 16;
            uint4 a0 = *(const uint4*)s0, b0 = *(const uint4*)(s0 + 8);
            uint4 a1 = *(const uint4*)(s0 + 64), b1 = *(const uint4*)(s0 + 72);
            pfA[0] = *(const uint4*)(s0 + 128); pfB[0] = *(const uint4*)(s0 + 136);
            char* d0 = (char*)aS[0] + wrow * 144 + wseg * 32;
            *(uint4*)d0 = a0; *(uint4*)(d0 + 16) = b0;
            char* d1 = (char*)aS[1] + wrow * 144 + wseg * 32;
            *(uint4*)d1 = a1; *(uint4*)(d1 + 16) = b1;
        }
        __syncthreads();

        f32x4 acc[2][2];
#pragma unroll
        for (int it = 0; it < 64; ++it) {
            const int cj = it >> 3, kt = it & 7;
            if (kt == 0) { acc[0][0] = zz; acc[0][1] = zz; acc[1][0] = zz; acc[1][1] = zz; }
            // issue global prefetch of W(it+3)
            if (it + 3 < 64) {
                int nit = it + 3;
                const u16* s = Wc + (size_t)(((nit >> 3) * 128 + wrow) * 512 + (nit & 7) * 64 + wseg * 16);
                pfA[(it + 1) & 1] = *(const uint4*)s;
                pfB[(it + 1) & 1] = *(const uint4*)(s + 8);
            }
            const char* aB = (const char*)aS[it % 3];
            const char* bB = (kt < 4) ? xSc : hSc;
#pragma unroll
            for (int ks = 0; ks < 2; ++ks) {
                bf16x8 av[2], bv[2];
#pragma unroll
                for (int m = 0; m < 2; ++m) {
                    int r = crow0 + m * 16 + lro;
                    av[m] = *(const bf16x8*)(aB + r * 144 + ks * 64 + q4 * 16);
                }
                const int cb = (kt & 3) * 8 + ks * 4 + q4;   // 16B chunk within 512B row
#pragma unroll
                for (int n = 0; n < 2; ++n) {
                    int row = bcol0 + n * 16 + lro;
                    int slot = (cb + row) & 31;
                    bv[n] = *(const bf16x8*)(bB + row * 512 + slot * 16);
                }
#pragma unroll
                for (int m = 0; m < 2; ++m)
#pragma unroll
                    for (int n = 0; n < 2; ++n)
                        acc[m][n] = __builtin_amdgcn_mfma_f32_16x16x32_bf16(av[m], bv[n], acc[m][n], 0, 0, 0);
            }
            // cell epilogue after K complete for this cj (pure VALU)
            if (kt == 7) {
#pragma unroll
                for (int m = 0; m < 2; ++m) {
                    int Crow = cj * 128 + crow0 + m * 16 + q4 * 4;
                    float4 bias = *(const float4*)(biasP + chain * 1024 + Crow);
                    unsigned int packed = 0;
#pragma unroll
                    for (int n = 0; n < 2; ++n) {
                        float zi = acc[m][n][0] + bias.x;
                        float zf = acc[m][n][1] + bias.y;
                        float zg = acc[m][n][2] + bias.z;
                        float zo = acc[m][n][3] + bias.w;
                        float cn = sigm(zf) * c_reg[cj][m * 2 + n] + sigm(zi) * tanh_(zg);
                        float hn = sigm(zo) * tanh_(cn);
                        c_reg[cj][m * 2 + n] = cn;
                        packed |= ((unsigned int)f2bf(hn)) << (16 * n);
                    }
                    hp[cj][m] = packed;
                }
            }
            __syncthreads();
            // write next weight buffer (data prefetched last iter)
            if (it + 2 < 64) {
                char* d = (char*)aS[(it + 2) % 3] + wrow * 144 + wseg * 32;
                *(uint4*)d = pfA[it & 1];
                *(uint4*)(d + 16) = pfB[it & 1];
            }
        }
        __syncthreads();                 // all hS/xS reads of this step done

        // ---- h-state scatter: paired shfl -> u32 writes, 2-way banks (free) ----
#pragma unroll
        for (int cj = 0; cj < 8; ++cj)
#pragma unroll
            for (int m = 0; m < 2; ++m) {
                int chunk = cj * 4 + wC;             // = jj>>3 (m*4+q4 <= 7)
                int jb = (m * 4 + q4) * 2;           // byte offset within 16B chunk
#pragma unroll
                for (int n = 0; n < 2; ++n) {
                    unsigned int val = (hp[cj][m] >> (16 * n)) & 0xffffu;
                    unsigned int other = (unsigned int)__shfl_xor((int)val, 16);
                    if ((q4 & 1) == 0) {             // even q4 -> even jj -> 4B aligned
                        int bl = bcol0 + n * 16 + lro;
                        int slot = (chunk + bl) & 31;
                        *(unsigned int*)(hSc + bl * 512 + slot * 16 + jb) = val | (other << 16);
                    }
                }
            }
        __syncthreads();                 // new h visible

        // ---- coalesced global outputs from hS (rotated, phase-conflict-free) ----
        if (chain < 2) {
            u16* dst = Y0 + ((size_t)(bi0 + srow) * 8 + t) * 512 + dir * 256;
#pragma unroll
            for (int i = 0; i < 4; ++i) {
                int c = i * 8 + sseg;
                int slot = (c + srow) & 31;
                *(uint4*)(dst + c * 8) = *(const uint4*)(hSc + srow * 512 + slot * 16);
            }
        } else if (t == slen - 1) {
            u16* dst = ylast + (size_t)((chain >> 1) - 1) * (NN * 512)
                     + (size_t)(bi0 + srow) * 512 + dir * 256;
#pragma unroll
            for (int i = 0; i < 4; ++i) {
                int c = i * 8 + sseg;
                int slot = (c + srow) & 31;
                *(uint4*)(dst + c * 8) = *(const uint4*)(hSc + srow * 512 + slot * 16);
            }
        }
        // next t's xS stage / aS prologue touch buffers whose readers finished above
    }
}

// ---------------- generic bf16 GEMM (A[M][K] @ BT[N][K]) -> f32 or bf16 C ----------------
__global__ __launch_bounds__(256)
void gemm_bf16(const u16* __restrict__ A, long long sAz,
               const u16* __restrict__ BT, long long sBz,
               void* __restrict__ Craw, long long sCz,
               const float* __restrict__ bias, int K, int obf) {
    __shared__ u16 As[128 * LDK];
    __shared__ u16 Bs[128 * LDK];
    const int z = blockIdx.z;
    A += z * sAz; BT += z * sBz;
    const int N = gridDim.y * 128;
    const int bm0 = blockIdx.x * 128;
    const int bn0 = blockIdx.y * 128;
    const int tid = threadIdx.x;
    const int l = tid & 63;
    const int wave = tid >> 6;
    const int wrow = (wave >> 1) * 64;
    const int wcol = (wave & 1) * 64;

    const u16* srcA[4]; const u16* srcB[4]; u16* dstA[4]; u16* dstB[4];
#pragma unroll
    for (int i = 0; i < 4; ++i) {
        int idx = i * 256 + tid;
        int row = idx >> 3;
        int kE = (idx & 7) * 8;
        srcA[i] = A + (long long)(bm0 + row) * K + kE;
        srcB[i] = BT + (long long)(bn0 + row) * K + kE;
        dstA[i] = As + row * LDK + kE;
        dstB[i] = Bs + row * LDK + kE;
    }
    f32x4 acc[4][4];
    const f32x4 zz = {0.f, 0.f, 0.f, 0.f};
#pragma unroll
    for (int m = 0; m < 4; ++m)
#pragma unroll
        for (int n = 0; n < 4; ++n) acc[m][n] = zz;

    for (int kk = 0; kk < K; kk += 64) {
#pragma unroll
        for (int i = 0; i < 4; ++i) {
            *(uint4*)dstA[i] = *(const uint4*)(srcA[i] + kk);
            *(uint4*)dstB[i] = *(const uint4*)(srcB[i] + kk);
        }
        __syncthreads();
        const int lro = l & 15;
        const int lk = (l >> 4) * 8;
#pragma unroll
        for (int k2 = 0; k2 < 64; k2 += 32) {
            bf16x8 av[4], bv[4];
#pragma unroll
            for (int m = 0; m < 4; ++m)
                av[m] = *(const bf16x8*)(As + (wrow + m * 16 + lro) * LDK + k2 + lk);
#pragma unroll
            for (int n = 0; n < 4; ++n)
                bv[n] = *(const bf16x8*)(Bs + (wcol + n * 16 + lro) * LDK + k2 + lk);
#pragma unroll
            for (int m = 0; m < 4; ++m)
#pragma unroll
                for (int n = 0; n < 4; ++n)
                    acc[m][n] = __builtin_amdgcn_mfma_f32_16x16x32_bf16(av[m], bv[n], acc[m][n], 0, 0, 0);
        }
        __syncthreads();
    }
#pragma unroll
    for (int m = 0; m < 4; ++m)
#pragma unroll
        for (int n = 0; n < 4; ++n) {
            int Cg = bn0 + wcol + n * 16 + (l & 15);
            float bv = bias ? bias[Cg] : 0.f;
#pragma unroll
            for (int r = 0; r < 4; ++r) {
                int R = bm0 + wrow + m * 16 + (l >> 4) * 4 + r;
                float v = acc[m][n][r] + bv;
                if (obf) ((u16*)Craw)[z * sCz + (long long)R * N + Cg] = f2bf(v);
                else     ((float*)Craw)[z * sCz + (long long)R * N + Cg] = v;
            }
        }
}

// ---------------- final per-level combine (permuted space, scatter to original) ----------------
__global__ void combine_level(const u16* __restrict__ G0, const u16* __restrict__ G13,
                              const u16* __restrict__ Wx, const int* __restrict__ ind,
                              const int* __restrict__ perm, const float* __restrict__ cprev,
                              float* __restrict__ outH, float* __restrict__ outC,
                              u16* __restrict__ hnext, float* __restrict__ cnext) {
    int i = blockIdx.x;
    int orig = perm[i];
    int j = threadIdx.x;
    float wf = bf2f(Wx[i * 1024 + j]);          // split order f,i,u,o
    float wi = bf2f(Wx[i * 1024 + 256 + j]);
    float wu = bf2f(Wx[i * 1024 + 512 + j]);
    float wo = bf2f(Wx[i * 1024 + 768 + j]);
    float bfa = 0.f;
#pragma unroll
    for (int k = 0; k < 8; ++k) {
        int iv = ind[orig * 8 + k];
        if (iv == -1) continue;
        float cc = (iv >= 1) ? cprev[(iv - 1) * 256 + j] : 0.f;
        bfa += sigm(wf + bf2f(G0[(i * 8 + k) * 256 + j])) * cc;
    }
    float bi = sigm(bf2f(G13[0 * NN * 256 + i * 256 + j]) + wi);
    float bu = tanh_(bf2f(G13[1 * NN * 256 + i * 256 + j]) + wu);
    float bo = sigm(bf2f(G13[2 * NN * 256 + i * 256 + j]) + wo);
    float nc = bi * bu + bfa;
    float nh = bo * tanh_(nc);
    outH[orig * 256 + j] = nh;
    outC[orig * 256 + j] = nc;
    hnext[orig * 256 + j] = f2bf(nh);
    cnext[orig * 256 + j] = nc;
}

extern "C" void kernel_launch(void* const* d_in, const int* in_sizes, int n_in,
                              void* d_out, int out_size, void* d_ws, size_t ws_size,
                              hipStream_t stream) {
    (void)in_sizes; (void)n_in; (void)out_size; (void)ws_size;
    const float* tensor  = (const float*)d_in[0];
    const int*   indices = (const int*)d_in[1];
    const float* Wk      = (const float*)d_in[2];
    const float* Wb      = (const float*)d_in[3];
    const float* kf      = (const float*)d_in[4];
    const float* rf      = (const float*)d_in[5];
    const float* bfw     = (const float*)d_in[6];
    const float* kb      = (const float*)d_in[7];
    const float* rb      = (const float*)d_in[8];
    const float* bbw     = (const float*)d_in[9];
    const float* ihf     = (const float*)d_in[10];
    const float* icf     = (const float*)d_in[11];
    const float* ihb     = (const float*)d_in[12];
    const float* icb     = (const float*)d_in[13];
    const float* fck     = (const float*)d_in[14];
    float* out = (float*)d_out;

    char* p = (char*)d_ws;
    auto take = [&](size_t bytes) -> char* {
        char* r = p;
        p += (bytes + 255) & ~(size_t)255;
        return r;
    };
    u16*   WcombT    = (u16*)  take(8ull * 1024 * 512 * 2);
    float* biasP     = (float*)take(8ull * 1024 * 4);
    u16*   WkT       = (u16*)  take(1024ull * 256 * 2);
    u16*   fcT       = (u16*)  take(4ull * 256 * 512 * 2);
    u16*   h0c       = (u16*)  take(8ull * 256 * 2);
    float* c0c       = (float*)take(8ull * 256 * 4);
    int*   perm      = (int*)  take((size_t)NLVL * NN * 4);
    int*   len_all   = (int*)  take((size_t)NLVL * NN * 4);
    int*   len_p     = (int*)  take((size_t)NLVL * NN * 4);
    int*   hist      = (int*)  take((size_t)NLVL * 8 * 4);
    u16*   Xbf       = (u16*)  take((size_t)NN * 256 * 2);
    u16*   Hc        = (u16*)  take((size_t)NN * 8 * 256 * 2);
    u16*   Y0        = (u16*)  take((size_t)NN * 8 * 512 * 2);
    u16*   ylast     = (u16*)  take(3ull * NN * 512 * 2);
    u16*   Wx        = (u16*)  take((size_t)NN * 1024 * 2);
    u16*   G0        = (u16*)  take((size_t)NN * 8 * 256 * 2);
    u16*   G13       = (u16*)  take(3ull * NN * 256 * 2);
    u16*   hprev[2]  = { (u16*)take((size_t)NN * 256 * 2), (u16*)take((size_t)NN * 256 * 2) };
    float* cprev[2]  = { (float*)take((size_t)NN * 256 * 4), (float*)take((size_t)NN * 256 * 4) };

    // one-time packing + length sort
    hipMemsetAsync(hist, 0, (size_t)NLVL * 8 * 4, stream);
    pack_wcomb<<<dim3(1024, 8), 256, 0, stream>>>(kf, rf, kb, rb, bfw, bbw, WcombT, biasP);
    pack_fcT<<<dim3(256, 4), 256, 0, stream>>>(fck, fcT);
    pack_wkT<<<dim3(1024), 256, 0, stream>>>(Wk, WkT);
    pack_init<<<dim3(8), 256, 0, stream>>>(ihf, icf, ihb, icb, h0c, c0c);
    compute_len<<<dim3(32, NLVL), 128, 0, stream>>>(indices, len_all, hist);
    build_perm<<<dim3(NLVL), 256, 0, stream>>>(len_all, hist, perm, len_p);

    for (int lvl = 0; lvl < NLVL; ++lvl) {
        const int* ind = indices + (size_t)lvl * NN * 8;
        const int* permL = perm + (size_t)lvl * NN;
        const int* lenpL = len_p + (size_t)lvl * NN;
        int cur = lvl & 1, nxt = cur ^ 1;

        convert_x<<<dim3(NN), 256, 0, stream>>>(tensor + (size_t)lvl * NN * 256, permL, Xbf);
        gather_children<<<dim3(NN), 256, 0, stream>>>(ind, permL, hprev[cur], Hc);

        // Wx = X @ W_kernel + W_bias   (M=4096, N=1024, K=256), permuted rows -> bf16
        gemm_bf16<<<dim3(32, 8, 1), 256, 0, stream>>>(Xbf, 0, WkT, 0, Wx, 0, Wb, 256, 1);

        // all recurrent steps, fused + persistent
        lstm_persist<<<dim3(512), 512, 0, stream>>>(Hc, WcombT, biasP, h0c, c0c, lenpL, Y0, ylast);

        // gate0 fc: [N*8, 512] @ fc0 -> G0 bf16   (M=32768, N=256, K=512)
        gemm_bf16<<<dim3(256, 2, 1), 256, 0, stream>>>(Y0, 0, fcT, 0, G0, 0, nullptr, 512, 1);
        // gates 1..3 fc: [N, 512] @ fc[g] -> G13[g-1] bf16   (batched over z)
        gemm_bf16<<<dim3(32, 2, 3), 256, 0, stream>>>(
            ylast, (long long)NN * 512, fcT + 256 * 512, (long long)256 * 512,
            G13, (long long)NN * 256, nullptr, 512, 1);

        combine_level<<<dim3(NN), 256, 0, stream>>>(
            G0, G13, Wx, ind, permL, cprev[cur],
            out + (size_t)lvl * NN * 256,
            out + (size_t)NLVL * NN * 256 + (size_t)lvl * NN * 256,
            hprev[nxt], cprev[nxt]);
    }
}